// Round 2
// baseline (266.680 us; speedup 1.0000x reference)
//
#include <hip/hip_runtime.h>

// Problem constants
#define B_SZ   8
#define T_SEQ  2048
#define C_DIM  1024
#define H_DIM  128

// KV-split chunking for attention
#define CHUNK      512            // keys per partial unit (8 tiles of 64)
#define NCMAX      4              // max chunks per strip = ceil(2048/512)
#define UNITS_PER_B 320           // sum_{s=0..127} ((s>>5)+1)

typedef _Float16 half8   __attribute__((ext_vector_type(8)));
typedef _Float16 half4_t __attribute__((ext_vector_type(4)));
typedef float    f32x4   __attribute__((ext_vector_type(4)));

#define MFMA(a, b, c) __builtin_amdgcn_mfma_f32_16x16x32_f16(a, b, c, 0, 0, 0)

// ---------------------------------------------------------------------------
// prep: W [C][H] fp32 -> WT [H][C] half (3 weights).  grid (512,3) x 256
// ---------------------------------------------------------------------------
__global__ __launch_bounds__(256) void prep_kernel(
    const float* __restrict__ Wk, const float* __restrict__ Wq,
    const float* __restrict__ Wv, _Float16* __restrict__ WT_all)
{
    const int w = blockIdx.y;
    const float* W = (w == 0) ? Wk : (w == 1) ? Wq : Wv;
    _Float16* dst = WT_all + (size_t)w * (C_DIM * H_DIM);
    int tid = blockIdx.x * 256 + threadIdx.x;
    int c = tid >> 7;
    int h = tid & (H_DIM - 1);
    dst[(size_t)h * C_DIM + c] = (_Float16)W[tid];
}

// ---------------------------------------------------------------------------
// proj: out[m][n] = sum_k x[m][k]*W[k][n], M=16384 K=1024 N=128.
// m-tile 64 for occupancy: grid (3,256) x 256 (4 waves, each 32m x 64n).
// w==0 -> k [B*T][H], w==1 -> q, w==2 -> vT [B][H][T] (transposed).
// ---------------------------------------------------------------------------
__global__ __launch_bounds__(256, 3) void proj_kernel(
    const float* __restrict__ x, const _Float16* __restrict__ WT_all,
    _Float16* __restrict__ q, _Float16* __restrict__ k, _Float16* __restrict__ vT)
{
    __shared__ _Float16 xs [64][72];    // 64 m-rows x 64 k (+8 pad)
    __shared__ _Float16 wsh[128][72];   // 128 n-rows x 64 k (+8 pad)

    const int w  = blockIdx.x;
    const int m0 = blockIdx.y * 64;
    const _Float16* WT = WT_all + (size_t)w * (C_DIM * H_DIM);

    const int t    = threadIdx.x;
    const int wave = t >> 6, lane = t & 63;
    const int quad = lane >> 4, l15 = lane & 15;
    const int wm = (wave >> 1) * 32;   // 0 or 32
    const int wn = (wave & 1) * 64;    // 0 or 64

    f32x4 acc[2][4] = {};

    for (int k0 = 0; k0 < C_DIM; k0 += 64) {
        __syncthreads();
        // stage x tile: 64 rows x 64 k, fp32 -> half
        {
            const int row_ = t >> 4, col = (t & 15) * 4;
            #pragma unroll
            for (int p = 0; p < 4; ++p) {
                int row = p * 16 + row_;
                float4 f = *(const float4*)(x + (size_t)(m0 + row) * C_DIM + k0 + col);
                half4_t hv = { (_Float16)f.x, (_Float16)f.y, (_Float16)f.z, (_Float16)f.w };
                *(half4_t*)(&xs[row][col]) = hv;
            }
        }
        // stage WT tile: 128 n-rows x 64 k (half, contiguous)
        {
            const int row_ = t >> 3, col = (t & 7) * 8;
            #pragma unroll
            for (int p = 0; p < 4; ++p) {
                int row = p * 32 + row_;
                *(half8*)(&wsh[row][col]) = *(const half8*)(WT + (size_t)row * C_DIM + k0 + col);
            }
        }
        __syncthreads();
        #pragma unroll
        for (int kb = 0; kb < 2; ++kb) {
            half8 af[2], bf[4];
            #pragma unroll
            for (int i = 0; i < 2; ++i)
                af[i] = *(const half8*)(&xs[wm + i * 16 + l15][kb * 32 + quad * 8]);
            #pragma unroll
            for (int j = 0; j < 4; ++j)
                bf[j] = *(const half8*)(&wsh[wn + j * 16 + l15][kb * 32 + quad * 8]);
            #pragma unroll
            for (int i = 0; i < 2; ++i)
                #pragma unroll
                for (int j = 0; j < 4; ++j)
                    acc[i][j] = MFMA(af[i], bf[j], acc[i][j]);
        }
    }

    if (w != 2) {
        _Float16* outN = (w == 0) ? k : q;
        #pragma unroll
        for (int i = 0; i < 2; ++i) {
            int row = m0 + wm + i * 16 + quad * 4;
            #pragma unroll
            for (int j = 0; j < 4; ++j) {
                int col = wn + j * 16 + l15;
                #pragma unroll
                for (int r = 0; r < 4; ++r)
                    outN[(size_t)(row + r) * H_DIM + col] = (_Float16)acc[i][j][r];
            }
        }
    } else {
        #pragma unroll
        for (int i = 0; i < 2; ++i) {
            int grow = m0 + wm + i * 16 + quad * 4;      // flattened b*T + t
            int bb = grow >> 11, tp = grow & (T_SEQ - 1);
            #pragma unroll
            for (int j = 0; j < 4; ++j) {
                int h = wn + j * 16 + l15;
                half4_t hv = { (_Float16)acc[i][j][0], (_Float16)acc[i][j][1],
                               (_Float16)acc[i][j][2], (_Float16)acc[i][j][3] };
                *(half4_t*)(vT + ((size_t)bb * H_DIM + h) * T_SEQ + tp) = hv;
            }
        }
    }
}

// ---------------------------------------------------------------------------
// attn_partial: one wave per (batch b, 16-row q-strip s, kv chunk c).
// grid (NCMAX, 128, 8) x 64; dead chunks exit immediately.
// K/V/Q fragments read directly from global (L2-resident); no barriers.
// Writes unnormalized partial O (half) + per-row (m, l) to workspace.
// ---------------------------------------------------------------------------
__global__ __launch_bounds__(64, 4) void attn_partial(
    const _Float16* __restrict__ q, const _Float16* __restrict__ k,
    const _Float16* __restrict__ vT,
    _Float16* __restrict__ pO, float* __restrict__ ml)
{
    const int c = blockIdx.x;
    const int s = 127 - blockIdx.y;     // heavy strips dispatch first
    const int b = blockIdx.z;
    if (32 * c > s) return;             // chunk start beyond strip's last row

    const int g   = s >> 5;             // chunks for this strip = g+1
    const int pid = b * UNITS_PER_B + 16 * g * (g + 1) + (s - 32 * g) * (g + 1) + c;

    const int lane = threadIdx.x;
    const int quad = lane >> 4, l15 = lane & 15;
    const int qrow0 = s * 16;

    const _Float16* qb = q  + (size_t)b * T_SEQ * H_DIM;
    const _Float16* kp = k  + (size_t)b * T_SEQ * H_DIM;
    const _Float16* vp = vT + (size_t)b * H_DIM * T_SEQ;

    __shared__ _Float16 ps[16][72];     // per-wave P transpose strip (C->A layout)

    // Q fragments (A layout): row m = l15, k = i*32 + quad*8 + j
    half8 aq[4];
    #pragma unroll
    for (int i = 0; i < 4; ++i)
        aq[i] = *(const half8*)(qb + (size_t)(qrow0 + l15) * H_DIM + i * 32 + quad * 8);

    f32x4 accO[8] = {};
    float mrun[4], lrun[4];
    #pragma unroll
    for (int r = 0; r < 4; ++r) { mrun[r] = -3.0e38f; lrun[r] = 0.0f; }

    const int rem = qrow0 + 15 - c * CHUNK;            // >= 0 for active chunks
    const int ntk = min(8, rem / 64 + 1);
    const float scale = 0.088388347648318447f;         // 1/sqrt(128)

    for (int kt = 0; kt < ntk; ++kt) {
        const int kv0 = c * CHUNK + kt * 64;

        // S = Q K^T : strip [16 x 64]; K B-fragments direct from global
        f32x4 sacc[4] = {};
        #pragma unroll
        for (int kbi = 0; kbi < 4; ++kbi) {
            #pragma unroll
            for (int nt = 0; nt < 4; ++nt) {
                half8 bf = *(const half8*)(kp + (size_t)(kv0 + nt * 16 + l15) * H_DIM
                                              + kbi * 32 + quad * 8);
                sacc[nt] = MFMA(aq[kbi], bf, sacc[nt]);
            }
        }

        // scale + causal mask (in place to limit VGPR pressure)
        if (kv0 + 63 <= qrow0) {
            #pragma unroll
            for (int nt = 0; nt < 4; ++nt)
                #pragma unroll
                for (int r = 0; r < 4; ++r)
                    sacc[nt][r] = sacc[nt][r] * scale;
        } else {
            #pragma unroll
            for (int nt = 0; nt < 4; ++nt) {
                int key = kv0 + nt * 16 + l15;
                #pragma unroll
                for (int r = 0; r < 4; ++r) {
                    int qr = qrow0 + quad * 4 + r;
                    sacc[nt][r] = (key <= qr) ? sacc[nt][r] * scale : -1.0e30f;
                }
            }
        }

        // online softmax; row r lives in lanes of this quad -> 16-lane reduce
        float mnew[4], alpha[4], rsum[4];
        #pragma unroll
        for (int r = 0; r < 4; ++r) {
            float rm = fmaxf(fmaxf(sacc[0][r], sacc[1][r]), fmaxf(sacc[2][r], sacc[3][r]));
            rm = fmaxf(rm, __shfl_xor(rm, 1));
            rm = fmaxf(rm, __shfl_xor(rm, 2));
            rm = fmaxf(rm, __shfl_xor(rm, 4));
            rm = fmaxf(rm, __shfl_xor(rm, 8));
            mnew[r]  = fmaxf(mrun[r], rm);
            alpha[r] = __expf(mrun[r] - mnew[r]);
            mrun[r]  = mnew[r];
            rsum[r]  = 0.0f;
        }
        #pragma unroll
        for (int nt = 0; nt < 4; ++nt)
            #pragma unroll
            for (int r = 0; r < 4; ++r) {
                float p = __expf(sacc[nt][r] - mnew[r]);
                rsum[r] += p;
                ps[quad * 4 + r][nt * 16 + l15] = (_Float16)p;   // C layout -> LDS
            }
        #pragma unroll
        for (int r = 0; r < 4; ++r) {
            rsum[r] += __shfl_xor(rsum[r], 1);
            rsum[r] += __shfl_xor(rsum[r], 2);
            rsum[r] += __shfl_xor(rsum[r], 4);
            rsum[r] += __shfl_xor(rsum[r], 8);
            lrun[r] = lrun[r] * alpha[r] + rsum[r];
        }
        #pragma unroll
        for (int nt = 0; nt < 8; ++nt)
            #pragma unroll
            for (int r = 0; r < 4; ++r)
                accO[nt][r] *= alpha[r];

        // O += P V : P back in A layout (intra-wave LDS RAW, no barrier);
        // V^T B-fragments direct from global
        half8 pf0 = *(const half8*)(&ps[l15][quad * 8]);
        half8 pf1 = *(const half8*)(&ps[l15][32 + quad * 8]);
        #pragma unroll
        for (int nt = 0; nt < 8; ++nt) {
            half8 vf0 = *(const half8*)(vp + (size_t)(nt * 16 + l15) * T_SEQ + kv0 + quad * 8);
            half8 vf1 = *(const half8*)(vp + (size_t)(nt * 16 + l15) * T_SEQ + kv0 + 32 + quad * 8);
            accO[nt] = MFMA(pf0, vf0, accO[nt]);
            accO[nt] = MFMA(pf1, vf1, accO[nt]);
        }
    }

    // store unnormalized partial O (half) + m,l
    #pragma unroll
    for (int nt = 0; nt < 8; ++nt)
        #pragma unroll
        for (int r = 0; r < 4; ++r)
            pO[(size_t)pid * 2048 + (quad * 4 + r) * 128 + nt * 16 + l15]
                = (_Float16)accO[nt][r];
    if (l15 == 0) {
        #pragma unroll
        for (int r = 0; r < 4; ++r) {
            ml[(size_t)pid * 32 + quad * 4 + r]      = mrun[r];
            ml[(size_t)pid * 32 + 16 + quad * 4 + r] = lrun[r];
        }
    }
}

// ---------------------------------------------------------------------------
// attn_combine: merge <=4 chunk partials per strip, normalize, write fp32 out.
// grid (128, 8) x 128
// ---------------------------------------------------------------------------
__global__ __launch_bounds__(128) void attn_combine(
    const _Float16* __restrict__ pO, const float* __restrict__ ml,
    float* __restrict__ out)
{
    const int s = blockIdx.x, b = blockIdx.y;
    const int g = s >> 5, nc = g + 1;
    const int base = b * UNITS_PER_B + 16 * g * (g + 1) + (s - 32 * g) * (g + 1);
    const int t = threadIdx.x;

    __shared__ float wsc[NCMAX][16];   // per-chunk weight / denom, per row

    if (t < 16) {
        float mv[NCMAX], lv[NCMAX];
        float M = -3.0e38f;
        for (int c = 0; c < nc; ++c) {
            mv[c] = ml[(size_t)(base + c) * 32 + t];
            lv[c] = ml[(size_t)(base + c) * 32 + 16 + t];
            M = fmaxf(M, mv[c]);
        }
        float denom = 0.0f;
        for (int c = 0; c < nc; ++c) {
            float wgt = __expf(mv[c] - M);
            denom += lv[c] * wgt;
            wsc[c][t] = wgt;
        }
        float inv = 1.0f / denom;
        for (int c = 0; c < nc; ++c) wsc[c][t] *= inv;
    }
    __syncthreads();

    const int h = t;   // 0..127
    for (int row = 0; row < 16; ++row) {
        float acc = 0.0f;
        for (int c = 0; c < nc; ++c)
            acc += wsc[c][row] * (float)pO[(size_t)(base + c) * 2048 + row * 128 + h];
        out[((size_t)b * T_SEQ + s * 16 + row) * H_DIM + h] = acc;
    }
}

// ---------------------------------------------------------------------------
extern "C" void kernel_launch(void* const* d_in, const int* in_sizes, int n_in,
                              void* d_out, int out_size, void* d_ws, size_t ws_size,
                              hipStream_t stream)
{
    const float* x  = (const float*)d_in[0];
    const float* Wk = (const float*)d_in[1];
    const float* Wq = (const float*)d_in[2];
    const float* Wv = (const float*)d_in[3];
    float* out = (float*)d_out;

    _Float16* ws = (_Float16*)d_ws;
    const size_t NQKV = (size_t)B_SZ * T_SEQ * H_DIM;          // 2,097,152
    _Float16* q_ws  = ws;
    _Float16* k_ws  = ws + NQKV;
    _Float16* vT_ws = ws + 2 * NQKV;
    _Float16* wt_ws = ws + 3 * NQKV;                           // 3*C*H halfs
    _Float16* pO_ws = wt_ws + 3 * (size_t)(C_DIM * H_DIM);     // 2560*2048 halfs
    float*    ml_ws = (float*)(pO_ws + (size_t)B_SZ * UNITS_PER_B * 2048);

    prep_kernel <<<dim3(512, 3),        256, 0, stream>>>(Wk, Wq, Wv, wt_ws);
    proj_kernel <<<dim3(3, 256),        256, 0, stream>>>(x, wt_ws, q_ws, k_ws, vT_ws);
    attn_partial<<<dim3(NCMAX, 128, 8),  64, 0, stream>>>(q_ws, k_ws, vT_ws, pO_ws, ml_ws);
    attn_combine<<<dim3(128, 8),        128, 0, stream>>>(pO_ws, ml_ws, out);
}

// Round 3
// 174.180 us; speedup vs baseline: 1.5311x; 1.5311x over previous
//
#include <hip/hip_runtime.h>

// Problem constants
#define B_SZ   8
#define T_SEQ  2048
#define C_DIM  1024
#define H_DIM  128

typedef _Float16 half8   __attribute__((ext_vector_type(8)));
typedef _Float16 half4_t __attribute__((ext_vector_type(4)));
typedef float    f32x4   __attribute__((ext_vector_type(4)));

#define MFMA(a, b, c) __builtin_amdgcn_mfma_f32_16x16x32_f16(a, b, c, 0, 0, 0)

// ---------------------------------------------------------------------------
// prep: W [C][H] fp32 -> WT [H][C] half (3 weights).  grid (512,3) x 256
// ---------------------------------------------------------------------------
__global__ __launch_bounds__(256) void prep_kernel(
    const float* __restrict__ Wk, const float* __restrict__ Wq,
    const float* __restrict__ Wv, _Float16* __restrict__ WT_all)
{
    const int w = blockIdx.y;
    const float* W = (w == 0) ? Wk : (w == 1) ? Wq : Wv;
    _Float16* dst = WT_all + (size_t)w * (C_DIM * H_DIM);
    int tid = blockIdx.x * 256 + threadIdx.x;
    int c = tid >> 7;
    int h = tid & (H_DIM - 1);
    dst[(size_t)h * C_DIM + c] = (_Float16)W[tid];
}

// ---------------------------------------------------------------------------
// proj: out[m][n] = sum_k x[m][k]*W[k][n], M=16384 K=1024 N=128.
// grid (3,256) x 256 (4 waves, each 32m x 64n).
// w==0 -> k [B*T][H], w==1 -> q, w==2 -> vT [B][H][T] (transposed).
// ---------------------------------------------------------------------------
__global__ __launch_bounds__(256, 3) void proj_kernel(
    const float* __restrict__ x, const _Float16* __restrict__ WT_all,
    _Float16* __restrict__ q, _Float16* __restrict__ k, _Float16* __restrict__ vT)
{
    __shared__ _Float16 xs [64][72];
    __shared__ _Float16 wsh[128][72];

    const int w  = blockIdx.x;
    const int m0 = blockIdx.y * 64;
    const _Float16* WT = WT_all + (size_t)w * (C_DIM * H_DIM);

    const int t    = threadIdx.x;
    const int wave = t >> 6, lane = t & 63;
    const int quad = lane >> 4, l15 = lane & 15;
    const int wm = (wave >> 1) * 32;
    const int wn = (wave & 1) * 64;

    f32x4 acc[2][4] = {};

    for (int k0 = 0; k0 < C_DIM; k0 += 64) {
        __syncthreads();
        {
            const int row_ = t >> 4, col = (t & 15) * 4;
            #pragma unroll
            for (int p = 0; p < 4; ++p) {
                int row = p * 16 + row_;
                float4 f = *(const float4*)(x + (size_t)(m0 + row) * C_DIM + k0 + col);
                half4_t hv = { (_Float16)f.x, (_Float16)f.y, (_Float16)f.z, (_Float16)f.w };
                *(half4_t*)(&xs[row][col]) = hv;
            }
        }
        {
            const int row_ = t >> 3, col = (t & 7) * 8;
            #pragma unroll
            for (int p = 0; p < 4; ++p) {
                int row = p * 32 + row_;
                *(half8*)(&wsh[row][col]) = *(const half8*)(WT + (size_t)row * C_DIM + k0 + col);
            }
        }
        __syncthreads();
        #pragma unroll
        for (int kb = 0; kb < 2; ++kb) {
            half8 af[2], bf[4];
            #pragma unroll
            for (int i = 0; i < 2; ++i)
                af[i] = *(const half8*)(&xs[wm + i * 16 + l15][kb * 32 + quad * 8]);
            #pragma unroll
            for (int j = 0; j < 4; ++j)
                bf[j] = *(const half8*)(&wsh[wn + j * 16 + l15][kb * 32 + quad * 8]);
            #pragma unroll
            for (int i = 0; i < 2; ++i)
                #pragma unroll
                for (int j = 0; j < 4; ++j)
                    acc[i][j] = MFMA(af[i], bf[j], acc[i][j]);
        }
    }

    if (w != 2) {
        _Float16* outN = (w == 0) ? k : q;
        #pragma unroll
        for (int i = 0; i < 2; ++i) {
            int row = m0 + wm + i * 16 + quad * 4;
            #pragma unroll
            for (int j = 0; j < 4; ++j) {
                int col = wn + j * 16 + l15;
                #pragma unroll
                for (int r = 0; r < 4; ++r)
                    outN[(size_t)(row + r) * H_DIM + col] = (_Float16)acc[i][j][r];
            }
        }
    } else {
        #pragma unroll
        for (int i = 0; i < 2; ++i) {
            int grow = m0 + wm + i * 16 + quad * 4;
            int bb = grow >> 11, tp = grow & (T_SEQ - 1);
            #pragma unroll
            for (int j = 0; j < 4; ++j) {
                int h = wn + j * 16 + l15;
                half4_t hv = { (_Float16)acc[i][j][0], (_Float16)acc[i][j][1],
                               (_Float16)acc[i][j][2], (_Float16)acc[i][j][3] };
                *(half4_t*)(vT + ((size_t)bb * H_DIM + h) * T_SEQ + tp) = hv;
            }
        }
    }
}

// ---------------------------------------------------------------------------
// attn: qtile=32 (2 waves x 16-row strip), kv tile 64, KV-split 2.
// 1D grid 768 x 128 threads. b = blk&7 -> XCD-batch affinity (per-XCD L2
// holds one batch's q/k/vT = 1.5 MB). u = blk>>3 heavy-first:
//   u<32 : qt=63-u, chunk 0 (16 tiles)     [partial]
//   u<64 : qt=95-u, chunk 1 (tiles 16..)   [partial]
//   else : qt=95-u, chunk 0 (all tiles)    [writes out directly]
// LDS 40448 B -> 4 blocks/CU; one batch (96 blocks) co-resident per XCD.
// ---------------------------------------------------------------------------
__global__ __launch_bounds__(128) void attn_kernel(
    const _Float16* __restrict__ q, const _Float16* __restrict__ k,
    const _Float16* __restrict__ vT,
    _Float16* __restrict__ pO, float* __restrict__ ml, float* __restrict__ out)
{
    __shared__ _Float16 ks [64][136];
    __shared__ _Float16 vts[128][72];
    __shared__ _Float16 ps [2][16][72];

    const int n = blockIdx.x;
    const int b = n & 7;
    const int u = n >> 3;
    int qt, c;
    if (u < 32)      { qt = 63 - u; c = 0; }
    else if (u < 64) { qt = 95 - u; c = 1; }
    else             { qt = 95 - u; c = 0; }
    const bool partial = (u < 64);

    const int ktEnd = qt >> 1;                       // last kv tile overall
    const int kt0 = c * 16;
    const int kt1 = (c == 0) ? min(15, ktEnd) : ktEnd;

    const int t = threadIdx.x;
    const int wave = t >> 6, lane = t & 63;
    const int quad = lane >> 4, l15 = lane & 15;
    const int qrow0 = qt * 32 + wave * 16;

    const _Float16* qb = q  + (size_t)b * T_SEQ * H_DIM;
    const _Float16* kp = k  + (size_t)b * T_SEQ * H_DIM;
    const _Float16* vp = vT + (size_t)b * H_DIM * T_SEQ;

    // Q fragments (A layout), pre-scaled by 1/sqrt(H)
    half8 aq[4];
    #pragma unroll
    for (int i = 0; i < 4; ++i) {
        half8 v = *(const half8*)(qb + (size_t)(qrow0 + l15) * H_DIM + i * 32 + quad * 8);
        #pragma unroll
        for (int j = 0; j < 8; ++j) v[j] = v[j] * (_Float16)0.088388347648318447f;
        aq[i] = v;
    }

    f32x4 accO[8] = {};
    float mrun[4], lrun[4];
    #pragma unroll
    for (int r = 0; r < 4; ++r) { mrun[r] = -3.0e38f; lrun[r] = 0.0f; }

    for (int kt = kt0; kt <= kt1; ++kt) {
        const int kv0 = kt * 64;
        __syncthreads();
        // stage K tile [64][128]
        {
            const int row_ = t >> 4, seg = t & 15;
            #pragma unroll
            for (int p = 0; p < 8; ++p) {
                int row = p * 8 + row_;
                *(half8*)(&ks[row][seg * 8]) =
                    *(const half8*)(kp + (size_t)(kv0 + row) * H_DIM + seg * 8);
            }
        }
        // stage V^T tile [128][64]
        {
            const int h_ = t >> 3, seg = t & 7;
            #pragma unroll
            for (int p = 0; p < 8; ++p) {
                int h = p * 16 + h_;
                *(half8*)(&vts[h][seg * 8]) =
                    *(const half8*)(vp + (size_t)h * T_SEQ + kv0 + seg * 8);
            }
        }
        __syncthreads();

        // S = Q K^T (Q pre-scaled)
        f32x4 sacc[4] = {};
        #pragma unroll
        for (int kbi = 0; kbi < 4; ++kbi) {
            #pragma unroll
            for (int nt = 0; nt < 4; ++nt) {
                half8 bf = *(const half8*)(&ks[nt * 16 + l15][kbi * 32 + quad * 8]);
                sacc[nt] = MFMA(aq[kbi], bf, sacc[nt]);
            }
        }

        // causal mask (only needed on/above diagonal tiles)
        if (kv0 + 63 > qrow0) {
            #pragma unroll
            for (int nt = 0; nt < 4; ++nt) {
                int key = kv0 + nt * 16 + l15;
                #pragma unroll
                for (int r = 0; r < 4; ++r) {
                    int qr = qrow0 + quad * 4 + r;
                    if (key > qr) sacc[nt][r] = -1.0e30f;
                }
            }
        }

        // online softmax (16-lane row reduce within quad group)
        float mnew[4], alpha[4], rsum[4];
        #pragma unroll
        for (int r = 0; r < 4; ++r) {
            float rm = fmaxf(fmaxf(sacc[0][r], sacc[1][r]), fmaxf(sacc[2][r], sacc[3][r]));
            rm = fmaxf(rm, __shfl_xor(rm, 1));
            rm = fmaxf(rm, __shfl_xor(rm, 2));
            rm = fmaxf(rm, __shfl_xor(rm, 4));
            rm = fmaxf(rm, __shfl_xor(rm, 8));
            mnew[r]  = fmaxf(mrun[r], rm);
            alpha[r] = __expf(mrun[r] - mnew[r]);
            mrun[r]  = mnew[r];
            rsum[r]  = 0.0f;
        }
        #pragma unroll
        for (int nt = 0; nt < 4; ++nt)
            #pragma unroll
            for (int r = 0; r < 4; ++r) {
                float p = __expf(sacc[nt][r] - mnew[r]);
                rsum[r] += p;
                ps[wave][quad * 4 + r][nt * 16 + l15] = (_Float16)p;
            }
        #pragma unroll
        for (int r = 0; r < 4; ++r) {
            rsum[r] += __shfl_xor(rsum[r], 1);
            rsum[r] += __shfl_xor(rsum[r], 2);
            rsum[r] += __shfl_xor(rsum[r], 4);
            rsum[r] += __shfl_xor(rsum[r], 8);
            lrun[r] = lrun[r] * alpha[r] + rsum[r];
        }
        #pragma unroll
        for (int nt = 0; nt < 8; ++nt)
            #pragma unroll
            for (int r = 0; r < 4; ++r)
                accO[nt][r] *= alpha[r];

        __syncthreads();   // ps visibility (cheap with 2 waves)

        // O += P V
        half8 pf0 = *(const half8*)(&ps[wave][l15][quad * 8]);
        half8 pf1 = *(const half8*)(&ps[wave][l15][32 + quad * 8]);
        #pragma unroll
        for (int nt = 0; nt < 8; ++nt) {
            half8 vf0 = *(const half8*)(&vts[nt * 16 + l15][quad * 8]);
            half8 vf1 = *(const half8*)(&vts[nt * 16 + l15][32 + quad * 8]);
            accO[nt] = MFMA(pf0, vf0, accO[nt]);
            accO[nt] = MFMA(pf1, vf1, accO[nt]);
        }
    }

    if (partial) {
        const int pid = b * 64 + u;
        const int wrow = wave * 16 + quad * 4;
        #pragma unroll
        for (int nt = 0; nt < 8; ++nt)
            #pragma unroll
            for (int r = 0; r < 4; ++r)
                pO[(size_t)pid * 4096 + (wrow + r) * 128 + nt * 16 + l15]
                    = (_Float16)accO[nt][r];
        if (l15 == 0) {
            #pragma unroll
            for (int r = 0; r < 4; ++r) {
                ml[(size_t)pid * 64 + wrow + r]      = mrun[r];
                ml[(size_t)pid * 64 + 32 + wrow + r] = lrun[r];
            }
        }
    } else {
        float invl[4];
        #pragma unroll
        for (int r = 0; r < 4; ++r) invl[r] = 1.0f / lrun[r];
        #pragma unroll
        for (int nt = 0; nt < 8; ++nt)
            #pragma unroll
            for (int r = 0; r < 4; ++r)
                out[((size_t)b * T_SEQ + qrow0 + quad * 4 + r) * H_DIM + nt * 16 + l15]
                    = accO[nt][r] * invl[r];
    }
}

// ---------------------------------------------------------------------------
// combine: merge the 2 chunk partials for qt>=32, normalize, write fp32 out.
// 1D grid 256 x 128; b = n&7 keeps pO reads XCD-local too.
// ---------------------------------------------------------------------------
__global__ __launch_bounds__(128) void attn_combine(
    const _Float16* __restrict__ pO, const float* __restrict__ ml,
    float* __restrict__ out)
{
    const int n = blockIdx.x;
    const int b = n & 7;
    const int qt = 32 + (n >> 3);
    const int pid0 = b * 64 + (63 - qt);
    const int pid1 = b * 64 + (95 - qt);
    const int t = threadIdx.x;

    __shared__ float w0s[32], w1s[32];

    if (t < 32) {
        float m0 = ml[(size_t)pid0 * 64 + t];
        float l0 = ml[(size_t)pid0 * 64 + 32 + t];
        float m1 = ml[(size_t)pid1 * 64 + t];
        float l1 = ml[(size_t)pid1 * 64 + 32 + t];
        float M  = fmaxf(m0, m1);
        float w0 = __expf(m0 - M), w1 = __expf(m1 - M);
        float inv = 1.0f / (l0 * w0 + l1 * w1);
        w0s[t] = w0 * inv;
        w1s[t] = w1 * inv;
    }
    __syncthreads();

    const int h = t;
    #pragma unroll 4
    for (int row = 0; row < 32; ++row) {
        float acc = w0s[row] * (float)pO[(size_t)pid0 * 4096 + row * 128 + h]
                  + w1s[row] * (float)pO[(size_t)pid1 * 4096 + row * 128 + h];
        out[((size_t)b * T_SEQ + qt * 32 + row) * H_DIM + h] = acc;
    }
}

// ---------------------------------------------------------------------------
extern "C" void kernel_launch(void* const* d_in, const int* in_sizes, int n_in,
                              void* d_out, int out_size, void* d_ws, size_t ws_size,
                              hipStream_t stream)
{
    const float* x  = (const float*)d_in[0];
    const float* Wk = (const float*)d_in[1];
    const float* Wq = (const float*)d_in[2];
    const float* Wv = (const float*)d_in[3];
    float* out = (float*)d_out;

    _Float16* ws = (_Float16*)d_ws;
    const size_t NQKV = (size_t)B_SZ * T_SEQ * H_DIM;          // 2,097,152
    _Float16* q_ws  = ws;
    _Float16* k_ws  = ws + NQKV;
    _Float16* vT_ws = ws + 2 * NQKV;
    _Float16* wt_ws = ws + 3 * NQKV;                           // 3*C*H halfs
    _Float16* pO_ws = wt_ws + 3 * (size_t)(C_DIM * H_DIM);     // 512 units * 4096 halfs
    float*    ml_ws = (float*)(pO_ws + (size_t)512 * 4096);

    prep_kernel <<<dim3(512, 3), 256, 0, stream>>>(Wk, Wq, Wv, wt_ws);
    proj_kernel <<<dim3(3, 256), 256, 0, stream>>>(x, wt_ws, q_ws, k_ws, vT_ws);
    attn_kernel <<<768, 128, 0, stream>>>(q_ws, k_ws, vT_ws, pO_ws, ml_ws, out);
    attn_combine<<<256, 128, 0, stream>>>(pO_ws, ml_ws, out);
}